// Round 4
// baseline (2582.077 us; speedup 1.0000x reference)
//
#include <hip/hip_runtime.h>
#include <hip/hip_bf16.h>
#include <math.h>

// B=16, S=4096, E=512, NW=8, H=64 -> M = B*S = 65536, K = 512.
// Pipeline:
//   1. cvt x (fp32->bf16), cvt4 weights                        [ws]
//   2. gemm<0> fused QKV: x@W{q,k,v}^T + b, cos(.+theta)       -> q,k,v bf16 [ws]
//   3. attn (16 tokens/block, 64 heads, d_k=8) -> rearranged bf16 (reuses xb)
//   4. gemm<1> attn_rs@Wo^T + bo -> fp32 d_out
//
// R3 post-mortem: epilogue scalar 2B scattered stores caused ~28x write
// amplification (1.8 GB/GEMM vs 64 MiB output; identical in R1+R3 -> epilogue,
// not staging). R4: (a) LDS-transpose epilogue w/ coalesced 16B/lane stores,
// (b) T2 XOR-swizzle on K-loop LDS (128B-row 16-way conflict, 3.8e7 measured),
// (c) T1 XCD-contiguous m-chunks (A fetched once per XCD),
// (d) attn rewritten: 16 tokens/block + LDS transpose -> 256B segment stores.

typedef __attribute__((ext_vector_type(8))) short short8;
typedef __attribute__((ext_vector_type(4))) float floatx4;

static __device__ __forceinline__ unsigned short f2bf(float f) {
  unsigned u = __float_as_uint(f);
  u += 0x7fffu + ((u >> 16) & 1u);   // RNE
  return (unsigned short)(u >> 16);
}
static __device__ __forceinline__ float bf2f(unsigned short h) {
  return __uint_as_float(((unsigned)h) << 16);
}

static __device__ __forceinline__ void gload16(const void* g, void* l) {
  __builtin_amdgcn_global_load_lds(
      (const __attribute__((address_space(1))) void*)g,
      (__attribute__((address_space(3))) void*)l, 16, 0, 0);
}

// ---------------- fp32 -> bf16 convert ----------------
__global__ void cvt_kernel(const float* __restrict__ in, unsigned short* __restrict__ out, int n) {
  int i0 = (blockIdx.x * blockDim.x + threadIdx.x) * 4;
  int stride = gridDim.x * blockDim.x * 4;
  for (int i = i0; i < n; i += stride) {
    const float4 v = *reinterpret_cast<const float4*>(in + i);
    ushort4 o;
    o.x = f2bf(v.x); o.y = f2bf(v.y); o.z = f2bf(v.z); o.w = f2bf(v.w);
    *reinterpret_cast<ushort4*>(out + i) = o;
  }
}

// all four 512x512 weights in one launch; out contiguous at wsel*262144
__global__ void cvt4_kernel(const float* __restrict__ w0, const float* __restrict__ w1,
                            const float* __restrict__ w2, const float* __restrict__ w3,
                            unsigned short* __restrict__ out) {
  const int wsel = blockIdx.x >> 6;
  const float* src = (wsel == 0) ? w0 : (wsel == 1) ? w1 : (wsel == 2) ? w2 : w3;
  const int base = (blockIdx.x & 63) * 4096 + threadIdx.x * 4;   // 4096 elems/block
  unsigned short* dst = out + wsel * 262144;
  #pragma unroll
  for (int it = 0; it < 4; ++it) {
    int i = base + it * 1024;
    const float4 v = *reinterpret_cast<const float4*>(src + i);
    ushort4 o;
    o.x = f2bf(v.x); o.y = f2bf(v.y); o.z = f2bf(v.z); o.w = f2bf(v.w);
    *reinterpret_cast<ushort4*>(dst + i) = o;
  }
}

// ---------------- bf16 MFMA GEMM ----------------
// MODE 0: fused QKV (W0=wq, wk/wv at +256K elems; o0=q, k/v at +32M). NBLK=12.
//         out = cos(acc + bias[n] + theta[n&7]) as bf16.
// MODE 1: out projection, outF = acc + bias[n] fp32. NBLK=4.
// 128x128 tile, BK=64, 4 waves (2x2), 4x4 16x16x32 frags.
// LDS: K-loop As/Bs linear [128][64] with XOR-chunk swizzle (rule #21:
// linear gload_lds dest + inverse-swizzled GLOBAL src + swizzled read).
// Epilogue: reuse LDS as per-wave 64x72 staging -> coalesced 16B/lane stores.
template<int MODE, int NBLK>
__global__ __launch_bounds__(256) void gemm_kernel(
    const unsigned short* __restrict__ A,    // [65536, 512] bf16
    const unsigned short* __restrict__ W0,   // [512,512] x (MODE0?3:1), row-major [n][k]
    const float* __restrict__ b0,
    const float* __restrict__ b1,
    const float* __restrict__ b2,
    const float* __restrict__ theta,
    unsigned short* __restrict__ o0,         // MODE 0
    float* __restrict__ outF)                // MODE 1
{
  constexpr int STAGE_BYTES = (MODE == 0) ? (4 * 64 * 72 * 2) : (4 * 64 * 72 * 4);
  constexpr int SMEM_BYTES = (STAGE_BYTES > 32768) ? STAGE_BYTES : 32768;
  __shared__ __align__(16) char smem[SMEM_BYTES];
  unsigned short* As = (unsigned short*)smem;      // [128*64]
  unsigned short* Bs = As + 128 * 64;

  const int tid = threadIdx.x;
  const int bid = blockIdx.x;

  // T1: XCD x owns contiguous m-chunk [x*64, x*64+64), n fastest inside.
  const int x = bid & 7;
  const int i_in = bid >> 3;                 // MODE0: [0,768)  MODE1: [0,256)
  int m_local, n_blk;
  if constexpr (MODE == 0) { m_local = i_in / 12; n_blk = i_in - m_local * 12; }
  else                     { m_local = i_in >> 2; n_blk = i_in & 3; }
  const int m0 = ((x << 6) + m_local) << 7;

  const unsigned short* W;
  const float* bias;
  int n0, wsel = 0;
  if constexpr (MODE == 0) {
    wsel = n_blk >> 2;                 // 0=Q 1=K 2=V
    n0 = (n_blk & 3) << 7;
    W = W0 + (size_t)wsel * 262144;
    bias = (wsel == 0) ? b0 : ((wsel == 1) ? b1 : b2);
  } else {
    W = W0; bias = b0; n0 = n_blk << 7;
  }

  const int lane = tid & 63;
  const int w = tid >> 6;
  const int wm = (w >> 1) << 6;
  const int wn = (w & 1) << 6;
  const int lr = lane & 15;
  const int kg = lane >> 4;
  const int r7a = lr & 7;

  // staging: chunk c=(i*4+w) -> 8 rows; lane -> row srow, 16B-slot (lane&7),
  // which must hold GLOBAL 16B-chunk (lane&7)^srow  (XOR swizzle, srow = row&7)
  const int srow = lane >> 3;
  const int scol = ((lane & 7) ^ srow) << 3;

  floatx4 acc[4][4] = {};

  for (int k0 = 0; k0 < 512; k0 += 64) {
    #pragma unroll
    for (int i = 0; i < 4; ++i) {
      const int chunk = (i << 2) | w;          // 0..15
      const int row = (chunk << 3) + srow;
      gload16(&A[(size_t)(m0 + row) * 512 + k0 + scol], &As[chunk << 9]);
      gload16(&W[(size_t)(n0 + row) * 512 + k0 + scol], &Bs[chunk << 9]);
    }
    __syncthreads();

    #pragma unroll
    for (int kk = 0; kk < 64; kk += 32) {
      short8 af[4], bfr[4];
      #pragma unroll
      for (int mi = 0; mi < 4; ++mi)
        af[mi] = *reinterpret_cast<const short8*>(
            &As[(wm + mi * 16 + lr) * 64 + (((kg + (kk >> 3)) ^ r7a) << 3)]);
      #pragma unroll
      for (int ni = 0; ni < 4; ++ni)
        bfr[ni] = *reinterpret_cast<const short8*>(
            &Bs[(wn + ni * 16 + lr) * 64 + (((kg + (kk >> 3)) ^ r7a) << 3)]);
      #pragma unroll
      for (int mi = 0; mi < 4; ++mi)
        #pragma unroll
        for (int ni = 0; ni < 4; ++ni)
          acc[mi][ni] = __builtin_amdgcn_mfma_f32_16x16x32_bf16(af[mi], bfr[ni], acc[mi][ni], 0, 0, 0);
    }
    __syncthreads();   // also protects epilogue LDS reuse
  }

  float bl[4];
  #pragma unroll
  for (int ni = 0; ni < 4; ++ni) bl[ni] = bias[n0 + wn + ni * 16 + lr];
  float thl = 0.0f;
  if constexpr (MODE == 0) thl = theta[lr & 7];   // gn === lr (mod 8)

  // stage per-wave 64x64 tile (row stride 72 keeps 16B row alignment)
  if constexpr (MODE == 0) {
    unsigned short* st = (unsigned short*)smem + w * (64 * 72);
    #pragma unroll
    for (int mi = 0; mi < 4; ++mi)
      #pragma unroll
      for (int ni = 0; ni < 4; ++ni)
        #pragma unroll
        for (int i = 0; i < 4; ++i)
          st[(mi * 16 + kg * 4 + i) * 72 + ni * 16 + lr] =
              f2bf(cosf(acc[mi][ni][i] + bl[ni] + thl));
    __syncthreads();
    unsigned short* dst = o0 + (size_t)wsel * 33554432;
    #pragma unroll
    for (int p = 0; p < 8; ++p) {
      const int rr = p * 8 + (lane >> 3);
      const int cc = (lane & 7) << 3;
      *reinterpret_cast<short8*>(&dst[(size_t)(m0 + wm + rr) * 512 + n0 + wn + cc]) =
          *reinterpret_cast<const short8*>(&st[rr * 72 + cc]);
    }
  } else {
    float* stf = (float*)smem + w * (64 * 72);
    #pragma unroll
    for (int mi = 0; mi < 4; ++mi)
      #pragma unroll
      for (int ni = 0; ni < 4; ++ni)
        #pragma unroll
        for (int i = 0; i < 4; ++i)
          stf[(mi * 16 + kg * 4 + i) * 72 + ni * 16 + lr] = acc[mi][ni][i] + bl[ni];
    __syncthreads();
    #pragma unroll
    for (int p = 0; p < 16; ++p) {
      const int rr = p * 4 + (lane >> 4);
      const int cc = (lane & 15) << 2;
      *reinterpret_cast<float4*>(&outF[(size_t)(m0 + wm + rr) * 512 + n0 + wn + cc]) =
          *reinterpret_cast<const float4*>(&stf[rr * 72 + cc]);
    }
  }
}

// ---------------- per-token cross-head attention ----------------
// Block = 16 consecutive (si-aligned) tokens; 4 waves x 4 tokens each.
// Per token: lane = head; scores[64] in registers. Output staged in LDS
// (XOR-swizzled) then written as full 256B row segments:
//   out[b][h*64 + sb][(g*16+si_l)*8 + d]
__global__ __launch_bounds__(256) void attn_kernel(
    const unsigned short* __restrict__ q,
    const unsigned short* __restrict__ k,
    const unsigned short* __restrict__ v,
    unsigned short* __restrict__ out)
{
  __shared__ float kf[4][64][9];
  __shared__ float vf[4][64][9];
  __shared__ unsigned short stg[64 * 128];   // [h][chunk si_l^(h&7)][8] bf16, 16 KB
  const int w = threadIdx.x >> 6;
  const int lane = threadIdx.x & 63;
  const int t0 = blockIdx.x * 16;

  #pragma unroll
  for (int it = 0; it < 4; ++it) {
    const int si_l = w * 4 + it;
    const int t = t0 + si_l;

    const size_t base = (size_t)t * 512 + lane * 8;
    short8 q8 = *reinterpret_cast<const short8*>(q + base);
    short8 k8 = *reinterpret_cast<const short8*>(k + base);
    short8 v8 = *reinterpret_cast<const short8*>(v + base);

    float qf[8];
    #pragma unroll
    for (int d = 0; d < 8; ++d) {
      qf[d] = bf2f((unsigned short)q8[d]);
      kf[w][lane][d] = bf2f((unsigned short)k8[d]);
      vf[w][lane][d] = bf2f((unsigned short)v8[d]);
    }
    __syncthreads();

    float s[64];
    #pragma unroll
    for (int j = 0; j < 64; ++j) {
      float a = 0.f;
      #pragma unroll
      for (int d = 0; d < 8; ++d) a += qf[d] * kf[w][j][d];
      s[j] = a;
    }
    float m = s[0];
    #pragma unroll
    for (int j = 1; j < 64; ++j) m = fmaxf(m, s[j]);

    const float c = 0.35355339059327f * 1.44269504089f;  // (1/sqrt(8)) * log2(e)
    float o[8] = {0, 0, 0, 0, 0, 0, 0, 0};
    float sum = 0.f;
    #pragma unroll
    for (int j = 0; j < 64; ++j) {
      float p = exp2f((s[j] - m) * c);
      sum += p;
      #pragma unroll
      for (int d = 0; d < 8; ++d) o[d] += p * vf[w][j][d];
    }
    const float inv = 1.0f / sum;

    short8 o8;
    #pragma unroll
    for (int d = 0; d < 8; ++d) o8[d] = (short)f2bf(o[d] * inv);
    const int chunk = si_l ^ (lane & 7);
    *reinterpret_cast<short8*>(&stg[lane * 128 + chunk * 8]) = o8;
    __syncthreads();
  }

  // write-out: 64 rows x 256 B; 4 passes x (16 rows x 16 lanes x 16 B)
  const int b = t0 >> 12;
  const int sidx = t0 & 4095;
  const int sb = sidx >> 6;
  const int g = (sidx >> 4) & 3;
  #pragma unroll
  for (int p = 0; p < 4; ++p) {
    const int h = p * 16 + (threadIdx.x >> 4);
    const int c = threadIdx.x & 15;
    short8 val = *reinterpret_cast<const short8*>(&stg[h * 128 + (c ^ (h & 7)) * 8]);
    const size_t row = (size_t)(b << 12) + (h << 6) + sb;
    *reinterpret_cast<short8*>(&out[row * 512 + (g * 16 + c) * 8]) = val;
  }
}

extern "C" void kernel_launch(void* const* d_in, const int* in_sizes, int n_in,
                              void* d_out, int out_size, void* d_ws, size_t ws_size,
                              hipStream_t stream) {
  const float* x     = (const float*)d_in[0];
  const float* Wq    = (const float*)d_in[1];
  const float* bq    = (const float*)d_in[2];
  const float* Wk    = (const float*)d_in[3];
  const float* bk    = (const float*)d_in[4];
  const float* Wv    = (const float*)d_in[5];
  const float* bv    = (const float*)d_in[6];
  const float* Wo    = (const float*)d_in[7];
  const float* bo    = (const float*)d_in[8];
  const float* theta = (const float*)d_in[9];
  float* out = (float*)d_out;

  char* ws = (char*)d_ws;
  const size_t MB = 1024ull * 1024ull;
  unsigned short* xb  = (unsigned short*)(ws);             // 64 MiB; reused as attn_rs
  unsigned short* qb  = (unsigned short*)(ws + 64 * MB);   // q,k,v contiguous (64 MiB each)
  unsigned short* wqb = (unsigned short*)(ws + 256 * MB);  // wq,wk,wv,wo contiguous

  const int NX = 65536 * 512;

  cvt_kernel<<<2048, 256, 0, stream>>>(x, xb, NX);
  cvt4_kernel<<<256, 256, 0, stream>>>(Wq, Wk, Wv, Wo, wqb);

  // fused QKV projection: N = 1536, grid = 8 XCD x 64 m x 12 n
  gemm_kernel<0, 12><<<6144, 256, 0, stream>>>(xb, wqb, bq, bk, bv, theta, qb, nullptr);

  attn_kernel<<<4096, 256, 0, stream>>>(qb, qb + 33554432, qb + 67108864, xb);

  // output projection: N = 512, grid = 8 x 64 x 4
  gemm_kernel<1, 4><<<2048, 256, 0, stream>>>(xb, wqb + 786432, bo, nullptr, nullptr, nullptr, nullptr, out);
}